// Round 7
// baseline (588.900 us; speedup 1.0000x reference)
//
#include <hip/hip_runtime.h>
#include <stdint.h>

#define N_NODES 100000
#define N_EDGES 600000
#define DIM_H   128
#define DIM_OUT 64
#define WPAD    136      // padded LDS row stride in ushort units (272B)
#define BN_EPS  1e-5f
#define NBLK    391      // ceil(N_NODES/256)
#define GRID64  1563     // ceil(N_NODES/64)

typedef __attribute__((ext_vector_type(8))) __bf16        bh8;
typedef __attribute__((ext_vector_type(4))) float         fl4;
typedef __attribute__((ext_vector_type(8))) unsigned short us8;
typedef __attribute__((ext_vector_type(4))) unsigned short us4;

__device__ __forceinline__ unsigned short f2bfbits(float f) {
  unsigned int u = __builtin_bit_cast(unsigned int, f);
  u += 0x7fffu + ((u >> 16) & 1u);           // RNE
  return (unsigned short)(u >> 16);
}
__device__ __forceinline__ float bf2f(unsigned short b) {
  unsigned int u = ((unsigned int)b) << 16;
  return __builtin_bit_cast(float, u);
}
// in-wave LDS producer->consumer fence (lanes of the same wave only)
__device__ __forceinline__ void wave_lds_fence() {
  asm volatile("s_waitcnt lgkmcnt(0)" ::: "memory");
  __builtin_amdgcn_sched_barrier(0);
}

// ---------------- weight prep (fragment-linear layout) + zero stats/deg ----------------
__global__ void prep_kernel(const float* __restrict__ cw1, const float* __restrict__ cw2,
                            const float* __restrict__ fc1w, const float* __restrict__ fc2w,
                            unsigned short* __restrict__ W1F, unsigned short* __restrict__ W2F,
                            unsigned short* __restrict__ F1F, unsigned short* __restrict__ F2F,
                            float* __restrict__ stats, int* __restrict__ deg) {
  int t = blockIdx.x * 256 + threadIdx.x;
  if (t < 3 * 16384) {
    int l = t >> 14, o = t & 16383;
    int j = o & 7, lane = (o >> 3) & 63, kk = (o >> 9) & 3, n0 = o >> 11;
    int k = kk * 32 + ((lane >> 4) << 3) + j;
    int n = (n0 << 4) + (lane & 15);
    W1F[t] = f2bfbits(cw1[l * 16384 + k * 128 + n]);
    W2F[t] = f2bfbits(cw2[l * 16384 + k * 128 + n]);
  }
  if (t < 16384) {
    int o = t;
    int j = o & 7, lane = (o >> 3) & 63, kk = (o >> 9) & 3, n0 = o >> 11;
    int k = kk * 32 + ((lane >> 4) << 3) + j;
    int n = (n0 << 4) + (lane & 15);
    F1F[t] = f2bfbits(fc1w[k * 128 + n]);
  }
  if (t < 8192) {
    int o = t;
    int j = o & 7, lane = (o >> 3) & 63, kk = (o >> 9) & 3, n0 = o >> 11;
    int k = kk * 32 + ((lane >> 4) << 3) + j;
    int n = (n0 << 4) + (lane & 15);                 // n < 64
    F2F[t] = f2bfbits(fc2w[k * 64 + n]);
  }
  if (t < 768)   stats[t] = 0.f;
  if (t < N_NODES) deg[t] = 0;
}

// ---------------- x->bf16 cast + degree count (merged) ----------------
__global__ void deg_xcast(const float* __restrict__ x, unsigned short* __restrict__ xB,
                          const int* __restrict__ ei, int* __restrict__ deg) {
  int i = blockIdx.x * 256 + threadIdx.x;    // 3.2M fl4 chunks exactly
  fl4 v = reinterpret_cast<const fl4*>(x)[i];
  us4 p;
#pragma unroll
  for (int j = 0; j < 4; ++j) p[j] = f2bfbits(v[j]);
  reinterpret_cast<us4*>(xB)[i] = p;
  if (i < N_EDGES) atomicAdd(&deg[ei[N_EDGES + i]], 1);
}

// ---------------- CSR build ----------------
__global__ void scanA(const int* __restrict__ deg, int* __restrict__ rowstart,
                      int* __restrict__ bsum) {
  __shared__ int s[256];
  int t = threadIdx.x, i = blockIdx.x * 256 + t;
  int v = (i < N_NODES) ? deg[i] : 0;
  s[t] = v;
  __syncthreads();
#pragma unroll
  for (int off = 1; off < 256; off <<= 1) {
    int u = (t >= off) ? s[t - off] : 0;
    __syncthreads();
    s[t] += u;
    __syncthreads();
  }
  if (i < N_NODES) rowstart[i] = s[t] - v;
  if (t == 0) bsum[blockIdx.x] = s[255];
}

__global__ void scanB(const int* __restrict__ bsum, int* __restrict__ boff) {
  __shared__ int s[512];
  int t = threadIdx.x;
  int v = (t < NBLK) ? bsum[t] : 0;
  s[t] = v;
  __syncthreads();
#pragma unroll
  for (int off = 1; off < 512; off <<= 1) {
    int u = (t >= off) ? s[t - off] : 0;
    __syncthreads();
    s[t] += u;
    __syncthreads();
  }
  if (t < NBLK) boff[t] = s[t] - v;   // exclusive
}

__global__ void scanC(int* __restrict__ rowstart, const int* __restrict__ boff,
                      int* __restrict__ cursor) {
  int i = blockIdx.x * 256 + threadIdx.x;
  if (i < N_NODES) {
    int v = rowstart[i] + boff[i >> 8];
    rowstart[i] = v;
    cursor[i] = v;
  }
  if (i == 0) rowstart[N_NODES] = N_EDGES;
}

__global__ void csr_fill(const int* __restrict__ ei, int* __restrict__ cursor,
                         int* __restrict__ csr_src) {
  int e = blockIdx.x * 256 + threadIdx.x;
  if (e < N_EDGES) {
    int pos = atomicAdd(&cursor[ei[N_EDGES + e]], 1);
    csr_src[pos] = ei[e];
  }
}

// ---------------- fused layer: gather(+BN-affine) -> MLP -> BN stats ----------------
// AFFINE=0: agg_i = sum over {i}∪N(i) of H_j           (layer 0, H = bf16 x)
// AFFINE=1: agg_i = s*sum(H_j) + cnt*b, s,b from stats (layers 1,2, H = prev z)
// then z = relu(relu(agg@W1+b1)@W2+b2) -> Z, accumulate sum/sumsq into stats_out.
template <int AFFINE>
__global__ __launch_bounds__(256, 4)
void layer_kernel(const unsigned short* __restrict__ H, const float* __restrict__ stats_in,
                  const float* __restrict__ gamma, const float* __restrict__ beta,
                  const int* __restrict__ rowstart, const int* __restrict__ csr,
                  const unsigned short* __restrict__ W1F, const float* __restrict__ b1,
                  const unsigned short* __restrict__ W2F, const float* __restrict__ b2,
                  unsigned short* __restrict__ Z, float* __restrict__ stats_out) {
  __shared__ __align__(16) unsigned short ybuf[64 * WPAD];    // 17408 B
  __shared__ float red[4][2][128];                            //  4096 B

  const int tid = threadIdx.x;
  const int wid = tid >> 6, lane = tid & 63;
  const int lr = lane & 15, lg = lane >> 4;
  const int row0 = blockIdx.x * 64;
  const int c = lane * 2;                   // this lane's 2 columns

  float sc0 = 1.f, sc1 = 1.f, bc0 = 0.f, bc1 = 0.f;
  if (AFFINE) {
    const float inv_n = 1.0f / (float)N_NODES;
    float m0 = stats_in[c] * inv_n, m1 = stats_in[c + 1] * inv_n;
    float v0 = stats_in[128 + c] * inv_n - m0 * m0;
    float v1 = stats_in[128 + c + 1] * inv_n - m1 * m1;
    sc0 = gamma[c] * rsqrtf(v0 + BN_EPS);
    sc1 = gamma[c + 1] * rsqrtf(v1 + BN_EPS);
    bc0 = beta[c] - m0 * sc0;
    bc1 = beta[c + 1] - m1 * sc1;
  }

  // ---- gather phase: this wave produces its own 16 agg rows into ybuf ----
  for (int rr = 0; rr < 16; ++rr) {
    int node = row0 + wid * 16 + rr;        // wave-uniform
    float a0 = 0.f, a1 = 0.f;
    if (node < N_NODES) {
      int rs = rowstart[node], re = rowstart[node + 1];
      int cnt = re - rs + 1;                // {self} + neighbors
      for (int i = 0; i < cnt; i += 4) {    // 4 row-loads in flight
#pragma unroll
        for (int u = 0; u < 4; ++u) {
          int m = i + u;
          if (m < cnt) {
            int idx = (m == 0) ? node : csr[rs + m - 1];
            unsigned int v = *reinterpret_cast<const unsigned int*>(H + (long)idx * DIM_H + c);
            a0 += bf2f((unsigned short)v);
            a1 += bf2f((unsigned short)(v >> 16));
          }
        }
      }
      if (AFFINE) {
        float fc = (float)cnt;
        a0 = sc0 * a0 + fc * bc0;
        a1 = sc1 * a1 + fc * bc1;
      }
    }
    unsigned int pk = ((unsigned int)f2bfbits(a1) << 16) | f2bfbits(a0);
    *reinterpret_cast<unsigned int*>(&ybuf[(wid * 16 + rr) * WPAD + c]) = pk;
  }
  wave_lds_fence();

  // ---- A fragments from own ybuf rows ----
  bh8 afrag[4];
#pragma unroll
  for (int kk = 0; kk < 4; ++kk)
    afrag[kk] = *reinterpret_cast<const bh8*>(
        &ybuf[(wid * 16 + lr) * WPAD + kk * 32 + 8 * lg]);
  wave_lds_fence();          // afrag in regs before ybuf overwrite

  // ---- GEMM1 + bias + relu -> ybuf (B from global L2, fragment-linear) ----
#pragma unroll
  for (int n0 = 0; n0 < 8; ++n0) {
    fl4 acc = {0.f, 0.f, 0.f, 0.f};
#pragma unroll
    for (int kk = 0; kk < 4; ++kk) {
      bh8 b = *reinterpret_cast<const bh8*>(&W1F[((n0 * 4 + kk) << 9) + lane * 8]);
      acc = __builtin_amdgcn_mfma_f32_16x16x32_bf16(afrag[kk], b, acc, 0, 0, 0);
    }
    float bias = b1[n0 * 16 + lr];
#pragma unroll
    for (int r = 0; r < 4; ++r) {
      float v = acc[r] + bias;
      v = v > 0.f ? v : 0.f;
      ybuf[(wid * 16 + 4 * lg + r) * WPAD + n0 * 16 + lr] = f2bfbits(v);
    }
  }
  wave_lds_fence();

  // ---- A2 fragments ----
  bh8 a2[4];
#pragma unroll
  for (int kk = 0; kk < 4; ++kk)
    a2[kk] = *reinterpret_cast<const bh8*>(
        &ybuf[(wid * 16 + lr) * WPAD + kk * 32 + 8 * lg]);
  wave_lds_fence();

  // ---- GEMM2 + bias + relu -> ybuf (z) + BN stats ----
#pragma unroll
  for (int n0 = 0; n0 < 8; ++n0) {
    fl4 acc = {0.f, 0.f, 0.f, 0.f};
#pragma unroll
    for (int kk = 0; kk < 4; ++kk) {
      bh8 b = *reinterpret_cast<const bh8*>(&W2F[((n0 * 4 + kk) << 9) + lane * 8]);
      acc = __builtin_amdgcn_mfma_f32_16x16x32_bf16(a2[kk], b, acc, 0, 0, 0);
    }
    float bias = b2[n0 * 16 + lr];
    float sp = 0.f, qp = 0.f;
#pragma unroll
    for (int r = 0; r < 4; ++r) {
      int row = row0 + wid * 16 + 4 * lg + r;
      float v = acc[r] + bias;
      v = v > 0.f ? v : 0.f;
      ybuf[(wid * 16 + 4 * lg + r) * WPAD + n0 * 16 + lr] = f2bfbits(v);
      if (row < N_NODES) { sp += v; qp += v * v; }
    }
    sp += __shfl_xor(sp, 16); sp += __shfl_xor(sp, 32);
    qp += __shfl_xor(qp, 16); qp += __shfl_xor(qp, 32);
    if (lg == 0) { red[wid][0][n0 * 16 + lr] = sp; red[wid][1][n0 * 16 + lr] = qp; }
  }
  wave_lds_fence();

  // ---- per-wave coalesced z store (own 16 rows) ----
#pragma unroll
  for (int i = 0; i < 4; ++i) {
    int ch = i * 64 + lane;               // 0..255
    int r  = wid * 16 + (ch >> 4);
    int c8 = (ch & 15) << 3;
    int row = row0 + r;
    if (row < N_NODES)
      *reinterpret_cast<uint4*>(&Z[(long)row * DIM_H + c8]) =
          *reinterpret_cast<const uint4*>(&ybuf[r * WPAD + c8]);
  }

  __syncthreads();           // cross-wave stats reduce

  {
    int which = tid >> 7, cc = tid & 127;
    float v = red[0][which][cc] + red[1][which][cc] + red[2][which][cc] + red[3][which][cc];
    unsafeAtomicAdd(&stats_out[which * 128 + cc], v);
  }
}

// ---------------- head: BN-affine -> fc1 -> relu -> dropout -> fc2 -> log_softmax ----------------
__global__ __launch_bounds__(256, 6)
void head_kernel(const unsigned short* __restrict__ Z, const float* __restrict__ stats,
                 const float* __restrict__ gamma, const float* __restrict__ beta,
                 const unsigned short* __restrict__ F1F, const float* __restrict__ fc1b,
                 const unsigned short* __restrict__ F2F, const float* __restrict__ fc2b,
                 const float* __restrict__ mask, float* __restrict__ out) {
  __shared__ __align__(16) unsigned short ybuf[64 * WPAD];    // 17408 B

  const int tid = threadIdx.x;
  const int wid = tid >> 6, lane = tid & 63;
  const int lr = lane & 15, lg = lane >> 4;
  const int row0 = blockIdx.x * 64;
  const float inv_n = 1.0f / (float)N_NODES;

  // A fragments: affine(z) in bf16
  bh8 afrag[4];
#pragma unroll
  for (int kk = 0; kk < 4; ++kk) {
    int k0 = kk * 32 + 8 * lg;
    fl4 s0, s1, bb0, bb1;
#pragma unroll
    for (int j = 0; j < 4; ++j) {
      int cc = k0 + j;
      float mean = stats[cc] * inv_n;
      float var  = stats[128 + cc] * inv_n - mean * mean;
      float sc   = gamma[cc] * rsqrtf(var + BN_EPS);
      s0[j] = sc; bb0[j] = beta[cc] - mean * sc;
    }
#pragma unroll
    for (int j = 0; j < 4; ++j) {
      int cc = k0 + 4 + j;
      float mean = stats[cc] * inv_n;
      float var  = stats[128 + cc] * inv_n - mean * mean;
      float sc   = gamma[cc] * rsqrtf(var + BN_EPS);
      s1[j] = sc; bb1[j] = beta[cc] - mean * sc;
    }
    int row = row0 + wid * 16 + lr;
    us8 t = (us8)0;
    if (row < N_NODES) {
      us8 zv = *reinterpret_cast<const us8*>(Z + (long)row * DIM_H + k0);
#pragma unroll
      for (int j = 0; j < 4; ++j) {
        t[j]     = f2bfbits(bf2f(zv[j])     * s0[j] + bb0[j]);
        t[4 + j] = f2bfbits(bf2f(zv[4 + j]) * s1[j] + bb1[j]);
      }
    }
    afrag[kk] = __builtin_bit_cast(bh8, t);
  }

  // GEMM1 + fc1b + relu + dropout -> ybuf
#pragma unroll
  for (int n0 = 0; n0 < 8; ++n0) {
    fl4 acc = {0.f, 0.f, 0.f, 0.f};
#pragma unroll
    for (int kk = 0; kk < 4; ++kk) {
      bh8 b = *reinterpret_cast<const bh8*>(&F1F[((n0 * 4 + kk) << 9) + lane * 8]);
      acc = __builtin_amdgcn_mfma_f32_16x16x32_bf16(afrag[kk], b, acc, 0, 0, 0);
    }
    float bias = fc1b[n0 * 16 + lr];
#pragma unroll
    for (int r = 0; r < 4; ++r) {
      int row = row0 + wid * 16 + 4 * lg + r;
      float v = acc[r] + bias;
      v = v > 0.f ? v : 0.f;
      float mk = (row < N_NODES) ? mask[(long)row * DIM_H + n0 * 16 + lr] : 0.f;
      ybuf[(wid * 16 + 4 * lg + r) * WPAD + n0 * 16 + lr] = f2bfbits(v * mk);
    }
  }
  wave_lds_fence();

  bh8 a2[4];
#pragma unroll
  for (int kk = 0; kk < 4; ++kk)
    a2[kk] = *reinterpret_cast<const bh8*>(
        &ybuf[(wid * 16 + lr) * WPAD + kk * 32 + 8 * lg]);

  // GEMM2 (N=64)
  fl4 acc2[4];
#pragma unroll
  for (int n0 = 0; n0 < 4; ++n0) {
    acc2[n0] = (fl4){0.f, 0.f, 0.f, 0.f};
#pragma unroll
    for (int kk = 0; kk < 4; ++kk) {
      bh8 b = *reinterpret_cast<const bh8*>(&F2F[((n0 * 4 + kk) << 9) + lane * 8]);
      acc2[n0] = __builtin_amdgcn_mfma_f32_16x16x32_bf16(a2[kk], b, acc2[n0], 0, 0, 0);
    }
    float bias = fc2b[n0 * 16 + lr];
#pragma unroll
    for (int r = 0; r < 4; ++r) acc2[n0][r] += bias;
  }

  // log_softmax over 64 cols + store
#pragma unroll
  for (int r = 0; r < 4; ++r) {
    float m = fmaxf(fmaxf(acc2[0][r], acc2[1][r]), fmaxf(acc2[2][r], acc2[3][r]));
#pragma unroll
    for (int d = 1; d < 16; d <<= 1) m = fmaxf(m, __shfl_xor(m, d, 16));
    float se = 0.f;
#pragma unroll
    for (int n0 = 0; n0 < 4; ++n0) se += __expf(acc2[n0][r] - m);
#pragma unroll
    for (int d = 1; d < 16; d <<= 1) se += __shfl_xor(se, d, 16);
    float lse = m + __logf(se);
    int row = row0 + wid * 16 + 4 * lg + r;
    if (row < N_NODES) {
#pragma unroll
      for (int n0 = 0; n0 < 4; ++n0)
        out[(long)row * DIM_OUT + n0 * 16 + lr] = acc2[n0][r] - lse;
    }
  }
}

// ---------------- launcher ----------------
extern "C" void kernel_launch(void* const* d_in, const int* in_sizes, int n_in,
                              void* d_out, int out_size, void* d_ws, size_t ws_size,
                              hipStream_t stream) {
  const float* x      = (const float*)d_in[0];
  const int*   ei     = (const int*)d_in[1];
  const float* cw1    = (const float*)d_in[2];
  const float* cb1    = (const float*)d_in[3];
  const float* cw2    = (const float*)d_in[4];
  const float* cb2    = (const float*)d_in[5];
  const float* gamma  = (const float*)d_in[6];
  const float* beta   = (const float*)d_in[7];
  const float* fc1w   = (const float*)d_in[8];
  const float* fc1b   = (const float*)d_in[9];
  const float* fc2w   = (const float*)d_in[10];
  const float* fc2b   = (const float*)d_in[11];
  const float* mask   = (const float*)d_in[12];
  float* out = (float*)d_out;

  char* ws = (char*)d_ws;
  unsigned short* Zalt  = (unsigned short*)ws;                 // 25,600,000 B (xB alias)
  unsigned short* Zb    = (unsigned short*)(ws + 25600000);    // 25,600,000 B
  unsigned short* W1F   = (unsigned short*)(ws + 51200000);    //     98,304 B
  unsigned short* W2F   = (unsigned short*)(ws + 51298304);    //     98,304 B
  unsigned short* F1F   = (unsigned short*)(ws + 51396608);    //     32,768 B
  unsigned short* F2F   = (unsigned short*)(ws + 51429376);    //     16,384 B
  float*          stats = (float*)(ws + 51445760);             //      3,072 B
  int*            rowst = (int*)(ws + 51448832);               //    400,004 B
  int*            cursor= (int*)(ws + 51848836);               //    400,000 B
  int*            csr   = (int*)(ws + 52248836);               //  2,400,000 B
  int*            bsum  = (int*)(ws + 54648836);               //      1,564 B
  int*            boff  = (int*)(ws + 54650400);               //      1,564 B
  if (ws_size < 54651964u) return;

  prep_kernel<<<NBLK, 256, 0, stream>>>(cw1, cw2, fc1w, fc2w, W1F, W2F, F1F, F2F,
                                        stats, cursor);        // cursor doubles as deg
  deg_xcast<<<12500, 256, 0, stream>>>(x, Zalt, ei, cursor);   // xB lives in Zalt

  scanA<<<NBLK, 256, 0, stream>>>(cursor, rowst, bsum);
  scanB<<<1, 512, 0, stream>>>(bsum, boff);
  scanC<<<NBLK, 256, 0, stream>>>(rowst, boff, cursor);
  csr_fill<<<2344, 256, 0, stream>>>(ei, cursor, csr);

  // layer 0: read xB (=Zalt), write Zb
  layer_kernel<0><<<GRID64, 256, 0, stream>>>(Zalt, nullptr, nullptr, nullptr, rowst, csr,
                                              W1F, cb1, W2F, cb2, Zb, stats);
  // layer 1: read Zb, write Zalt (xB dead)
  layer_kernel<1><<<GRID64, 256, 0, stream>>>(Zb, stats, gamma, beta, rowst, csr,
                                              W1F + 16384, cb1 + 128, W2F + 16384, cb2 + 128,
                                              Zalt, stats + 256);
  // layer 2: read Zalt, write Zb
  layer_kernel<1><<<GRID64, 256, 0, stream>>>(Zalt, stats + 256, gamma + 128, beta + 128,
                                              rowst, csr,
                                              W1F + 32768, cb1 + 256, W2F + 32768, cb2 + 256,
                                              Zb, stats + 512);
  // head: read Zb
  head_kernel<<<GRID64, 256, 0, stream>>>(Zb, stats + 512, gamma + 256, beta + 256,
                                          F1F, fc1b, F2F, fc2b, mask, out);
}

// Round 9
// 356.653 us; speedup vs baseline: 1.6512x; 1.6512x over previous
//
#include <hip/hip_runtime.h>
#include <stdint.h>

#define N_NODES 100000
#define N_EDGES 600000
#define DIM_H   128
#define DIM_OUT 64
#define WPAD    136      // padded LDS row stride in ushort units (272B)
#define BN_EPS  1e-5f
#define NBLK    391      // ceil(N_NODES/256)
#define GRID64_HEAD 1563 // ceil(N_NODES/64)

typedef __attribute__((ext_vector_type(8))) __bf16        bh8;
typedef __attribute__((ext_vector_type(4))) float         fl4;
typedef __attribute__((ext_vector_type(8))) unsigned short us8;
typedef __attribute__((ext_vector_type(4))) unsigned short us4;

__device__ __forceinline__ unsigned short f2bfbits(float f) {
  unsigned int u = __builtin_bit_cast(unsigned int, f);
  u += 0x7fffu + ((u >> 16) & 1u);           // RNE
  return (unsigned short)(u >> 16);
}
__device__ __forceinline__ float bf2f(unsigned short b) {
  unsigned int u = ((unsigned int)b) << 16;
  return __builtin_bit_cast(float, u);
}
// in-wave LDS producer->consumer fence (lanes of the same wave only)
__device__ __forceinline__ void wave_lds_fence() {
  asm volatile("s_waitcnt lgkmcnt(0)" ::: "memory");
  __builtin_amdgcn_sched_barrier(0);
}

// ---------------- weight prep (fragment-linear layout) + zero stats/deg ----------------
__global__ void prep_kernel(const float* __restrict__ cw1, const float* __restrict__ cw2,
                            const float* __restrict__ fc1w, const float* __restrict__ fc2w,
                            unsigned short* __restrict__ W1F, unsigned short* __restrict__ W2F,
                            unsigned short* __restrict__ F1F, unsigned short* __restrict__ F2F,
                            float* __restrict__ stats, int* __restrict__ deg) {
  int t = blockIdx.x * 256 + threadIdx.x;
  if (t < 3 * 16384) {
    int l = t >> 14, o = t & 16383;
    int j = o & 7, lane = (o >> 3) & 63, kk = (o >> 9) & 3, n0 = o >> 11;
    int k = kk * 32 + ((lane >> 4) << 3) + j;
    int n = (n0 << 4) + (lane & 15);
    W1F[t] = f2bfbits(cw1[l * 16384 + k * 128 + n]);
    W2F[t] = f2bfbits(cw2[l * 16384 + k * 128 + n]);
  }
  if (t < 16384) {
    int o = t;
    int j = o & 7, lane = (o >> 3) & 63, kk = (o >> 9) & 3, n0 = o >> 11;
    int k = kk * 32 + ((lane >> 4) << 3) + j;
    int n = (n0 << 4) + (lane & 15);
    F1F[t] = f2bfbits(fc1w[k * 128 + n]);
  }
  if (t < 8192) {
    int o = t;
    int j = o & 7, lane = (o >> 3) & 63, kk = (o >> 9) & 3, n0 = o >> 11;
    int k = kk * 32 + ((lane >> 4) << 3) + j;
    int n = (n0 << 4) + (lane & 15);                 // n < 64
    F2F[t] = f2bfbits(fc2w[k * 64 + n]);
  }
  if (t < 768)   stats[t] = 0.f;
  if (t < N_NODES) deg[t] = 0;
}

// ---------------- x->bf16 cast + degree count + dropout bitmask pack ----------------
__global__ void deg_xcast(const float* __restrict__ x, unsigned short* __restrict__ xB,
                          const int* __restrict__ ei, int* __restrict__ deg,
                          const float* __restrict__ mask, unsigned int* __restrict__ bmask) {
  int i = blockIdx.x * 256 + threadIdx.x;    // 3.2M fl4 chunks exactly
  fl4 v = reinterpret_cast<const fl4*>(x)[i];
  us4 p;
#pragma unroll
  for (int j = 0; j < 4; ++j) p[j] = f2bfbits(v[j]);
  reinterpret_cast<us4*>(xB)[i] = p;
  if (i < N_EDGES) atomicAdd(&deg[ei[N_EDGES + i]], 1);
  if (i < N_NODES * 4) {                     // one dword of bitmask = 32 cols
    const float* mp = mask + (long)i * 32;
    unsigned int b = 0;
#pragma unroll
    for (int j8 = 0; j8 < 8; ++j8) {
      fl4 mv = *reinterpret_cast<const fl4*>(mp + j8 * 4);
      b |= (mv[0] > 0.f ? 1u : 0u) << (j8 * 4 + 0);
      b |= (mv[1] > 0.f ? 1u : 0u) << (j8 * 4 + 1);
      b |= (mv[2] > 0.f ? 1u : 0u) << (j8 * 4 + 2);
      b |= (mv[3] > 0.f ? 1u : 0u) << (j8 * 4 + 3);
    }
    bmask[i] = b;
  }
}

// ---------------- CSR build ----------------
__global__ void scanA(const int* __restrict__ deg, int* __restrict__ rowstart,
                      int* __restrict__ bsum) {
  __shared__ int s[256];
  int t = threadIdx.x, i = blockIdx.x * 256 + t;
  int v = (i < N_NODES) ? deg[i] : 0;
  s[t] = v;
  __syncthreads();
#pragma unroll
  for (int off = 1; off < 256; off <<= 1) {
    int u = (t >= off) ? s[t - off] : 0;
    __syncthreads();
    s[t] += u;
    __syncthreads();
  }
  if (i < N_NODES) rowstart[i] = s[t] - v;
  if (t == 0) bsum[blockIdx.x] = s[255];
}

__global__ void scanB(const int* __restrict__ bsum, int* __restrict__ boff) {
  __shared__ int s[512];
  int t = threadIdx.x;
  int v = (t < NBLK) ? bsum[t] : 0;
  s[t] = v;
  __syncthreads();
#pragma unroll
  for (int off = 1; off < 512; off <<= 1) {
    int u = (t >= off) ? s[t - off] : 0;
    __syncthreads();
    s[t] += u;
    __syncthreads();
  }
  if (t < NBLK) boff[t] = s[t] - v;   // exclusive
}

__global__ void scanC(int* __restrict__ rowstart, const int* __restrict__ boff,
                      int* __restrict__ cursor) {
  int i = blockIdx.x * 256 + threadIdx.x;
  if (i < N_NODES) {
    int v = rowstart[i] + boff[i >> 8];
    rowstart[i] = v;
    cursor[i] = v;
  }
  if (i == 0) rowstart[N_NODES] = N_EDGES;
}

__global__ void csr_fill(const int* __restrict__ ei, int* __restrict__ cursor,
                         int* __restrict__ csr_src) {
  int e = blockIdx.x * 256 + threadIdx.x;
  if (e < N_EDGES) {
    int pos = atomicAdd(&cursor[ei[N_EDGES + e]], 1);
    csr_src[pos] = ei[e];
  }
}

// ---------------- gather: one node per wave; quarter-wave = one 256B row ----------------
// indices preloaded coalesced (one per lane) and shfl-broadcast; 8 rows in flight.
// AFFINE=0: agg = sum over {i}∪N(i) of H_j
// AFFINE=1: agg = s*sum(H_j) + cnt*b  (s,b from BN stats)
template <int AFFINE>
__global__ __launch_bounds__(256)
void gather_h(const unsigned short* __restrict__ H, const float* __restrict__ stats,
              const float* __restrict__ gamma, const float* __restrict__ beta,
              const int* __restrict__ rowstart, const int* __restrict__ csr,
              unsigned short* __restrict__ aggB) {
  int node = blockIdx.x * 4 + (threadIdx.x >> 6);   // grid*4 == N_NODES exactly
  int lane = threadIdx.x & 63;
  int q = lane >> 4, lc = lane & 15;
  int c = lc * 8;                        // 8 bf16 cols/lane; 16 lanes cover the row

  fl4 scA, scB, bcA, bcB;
  if (AFFINE) {
    const float inv_n = 1.0f / (float)N_NODES;
    fl4 s0 = *reinterpret_cast<const fl4*>(stats + c);
    fl4 s1 = *reinterpret_cast<const fl4*>(stats + c + 4);
    fl4 q0 = *reinterpret_cast<const fl4*>(stats + 128 + c);
    fl4 q1 = *reinterpret_cast<const fl4*>(stats + 128 + c + 4);
    fl4 g0 = *reinterpret_cast<const fl4*>(gamma + c);
    fl4 g1 = *reinterpret_cast<const fl4*>(gamma + c + 4);
    fl4 t0 = *reinterpret_cast<const fl4*>(beta + c);
    fl4 t1 = *reinterpret_cast<const fl4*>(beta + c + 4);
#pragma unroll
    for (int j = 0; j < 4; ++j) {
      float m = s0[j] * inv_n; float v = q0[j] * inv_n - m * m;
      scA[j] = g0[j] * rsqrtf(v + BN_EPS); bcA[j] = t0[j] - m * scA[j];
      m = s1[j] * inv_n; v = q1[j] * inv_n - m * m;
      scB[j] = g1[j] * rsqrtf(v + BN_EPS); bcB[j] = t1[j] - m * scB[j];
    }
  }

  int rs = rowstart[node], re = rowstart[node + 1];
  int cnt = re - rs + 1;                 // {self} + neighbors
  float acc[8] = {0.f, 0.f, 0.f, 0.f, 0.f, 0.f, 0.f, 0.f};

  for (int base = 0; base < cnt; base += 64) {
    int item = base + lane;
    int myidx = (item == 0) ? node : ((item < cnt) ? csr[rs + item - 1] : 0);
    int lim = cnt - base; if (lim > 64) lim = 64;
    for (int sub = 0; sub < lim; sub += 8) {
      int m0 = sub + q, m1 = sub + 4 + q;
      int i0 = __shfl(myidx, m0);
      int i1 = __shfl(myidx, m1);
      us8 r0 = (us8)0, r1 = (us8)0;
      if (m0 < lim) r0 = *reinterpret_cast<const us8*>(H + (long)i0 * DIM_H + c);
      if (m1 < lim) r1 = *reinterpret_cast<const us8*>(H + (long)i1 * DIM_H + c);
#pragma unroll
      for (int j = 0; j < 8; ++j) acc[j] += bf2f(r0[j]) + bf2f(r1[j]);
    }
  }

#pragma unroll
  for (int j = 0; j < 8; ++j) {
    acc[j] += __shfl_xor(acc[j], 16);
    acc[j] += __shfl_xor(acc[j], 32);
  }

  if (q == 0) {
    us8 pk;
    if (AFFINE) {
      float fc = (float)cnt;
#pragma unroll
      for (int j = 0; j < 4; ++j) {
        pk[j]     = f2bfbits(scA[j] * acc[j]     + fc * bcA[j]);
        pk[4 + j] = f2bfbits(scB[j] * acc[4 + j] + fc * bcB[j]);
      }
    } else {
#pragma unroll
      for (int j = 0; j < 8; ++j) pk[j] = f2bfbits(acc[j]);
    }
    *reinterpret_cast<us8*>(aggB + (long)node * DIM_H + c) = pk;
  }
}

// ---------------- fused GIN MLP: weights from L2 (fragment-linear), 4 blocks/CU ----------------
__global__ __launch_bounds__(256, 4)
void mlp_kernel(const unsigned short* __restrict__ A,
                const unsigned short* __restrict__ W1F, const float* __restrict__ b1,
                const unsigned short* __restrict__ W2F, const float* __restrict__ b2,
                unsigned short* __restrict__ Z, float* __restrict__ stats) {
  __shared__ __align__(16) unsigned short ybuf[128 * WPAD];   // 34816 B
  __shared__ float red[4][2][128];                            //  4096 B

  const int tid = threadIdx.x;
  const int wid = tid >> 6, lane = tid & 63;
  const int lr = lane & 15, lg = lane >> 4;
  const int row0 = blockIdx.x * 128;

  // A fragments straight from bf16 global
  bh8 afrag[2][4];
#pragma unroll
  for (int rt = 0; rt < 2; ++rt) {
    int row = row0 + wid * 32 + rt * 16 + lr;
    bool valid = row < N_NODES;
    const unsigned short* ap = A + (long)row * DIM_H;
#pragma unroll
    for (int kk = 0; kk < 4; ++kk) {
      us8 t = (us8)0;
      if (valid) t = *reinterpret_cast<const us8*>(ap + kk * 32 + 8 * lg);
      afrag[rt][kk] = __builtin_bit_cast(bh8, t);
    }
  }

  // GEMM1 + bias + relu -> ybuf (bf16); B-fragments: contiguous 1KB burst per (n0,kk)
#pragma unroll
  for (int n0 = 0; n0 < 8; ++n0) {
    fl4 acc[2] = {{0,0,0,0},{0,0,0,0}};
#pragma unroll
    for (int kk = 0; kk < 4; ++kk) {
      bh8 b = *reinterpret_cast<const bh8*>(&W1F[((n0 * 4 + kk) << 9) + lane * 8]);
      acc[0] = __builtin_amdgcn_mfma_f32_16x16x32_bf16(afrag[0][kk], b, acc[0], 0, 0, 0);
      acc[1] = __builtin_amdgcn_mfma_f32_16x16x32_bf16(afrag[1][kk], b, acc[1], 0, 0, 0);
    }
    float bias = b1[n0 * 16 + lr];
#pragma unroll
    for (int rt = 0; rt < 2; ++rt)
#pragma unroll
      for (int r = 0; r < 4; ++r) {
        float v = acc[rt][r] + bias;
        v = v > 0.f ? v : 0.f;
        ybuf[(wid * 32 + rt * 16 + 4 * lg + r) * WPAD + n0 * 16 + lr] = f2bfbits(v);
      }
  }

  wave_lds_fence();          // own-wave rows only

  // A2 fragments from ybuf
  bh8 a2[2][4];
#pragma unroll
  for (int rt = 0; rt < 2; ++rt)
#pragma unroll
    for (int kk = 0; kk < 4; ++kk)
      a2[rt][kk] = *reinterpret_cast<const bh8*>(
          &ybuf[(wid * 32 + rt * 16 + lr) * WPAD + kk * 32 + 8 * lg]);

  wave_lds_fence();          // a2 in regs before ybuf overwrite

  // GEMM2 + bias + relu -> ybuf (z), accumulate BN stats
#pragma unroll
  for (int n0 = 0; n0 < 8; ++n0) {
    fl4 acc[2] = {{0,0,0,0},{0,0,0,0}};
#pragma unroll
    for (int kk = 0; kk < 4; ++kk) {
      bh8 b = *reinterpret_cast<const bh8*>(&W2F[((n0 * 4 + kk) << 9) + lane * 8]);
      acc[0] = __builtin_amdgcn_mfma_f32_16x16x32_bf16(a2[0][kk], b, acc[0], 0, 0, 0);
      acc[1] = __builtin_amdgcn_mfma_f32_16x16x32_bf16(a2[1][kk], b, acc[1], 0, 0, 0);
    }
    float bias = b2[n0 * 16 + lr];
    float sp = 0.f, qp = 0.f;
#pragma unroll
    for (int rt = 0; rt < 2; ++rt)
#pragma unroll
      for (int r = 0; r < 4; ++r) {
        int row = row0 + wid * 32 + rt * 16 + 4 * lg + r;
        float v = acc[rt][r] + bias;
        v = v > 0.f ? v : 0.f;
        ybuf[(wid * 32 + rt * 16 + 4 * lg + r) * WPAD + n0 * 16 + lr] = f2bfbits(v);
        if (row < N_NODES) { sp += v; qp += v * v; }
      }
    sp += __shfl_xor(sp, 16); sp += __shfl_xor(sp, 32);
    qp += __shfl_xor(qp, 16); qp += __shfl_xor(qp, 32);
    if (lg == 0) { red[wid][0][n0 * 16 + lr] = sp; red[wid][1][n0 * 16 + lr] = qp; }
  }

  wave_lds_fence();

  // per-wave coalesced z store (own 32 rows)
#pragma unroll
  for (int i = 0; i < 8; ++i) {
    int ch = i * 64 + lane;               // 0..511
    int r  = wid * 32 + (ch >> 4);
    int c8 = (ch & 15) << 3;
    int row = row0 + r;
    if (row < N_NODES)
      *reinterpret_cast<uint4*>(&Z[(long)row * DIM_H + c8]) =
          *reinterpret_cast<const uint4*>(&ybuf[r * WPAD + c8]);
  }

  __syncthreads();           // only cross-wave dependency: stats reduce

  {
    int which = tid >> 7, cc = tid & 127;
    float v = red[0][which][cc] + red[1][which][cc] + red[2][which][cc] + red[3][which][cc];
    unsafeAtomicAdd(&stats[which * 128 + cc], v);
  }
}

// ---------------- head: BN-affine -> fc1 -> relu -> dropout(bitmask) -> fc2 -> log_softmax ----
__global__ __launch_bounds__(256, 6)
void head_kernel(const unsigned short* __restrict__ Z, const float* __restrict__ stats,
                 const float* __restrict__ gamma, const float* __restrict__ beta,
                 const unsigned short* __restrict__ F1F, const float* __restrict__ fc1b,
                 const unsigned short* __restrict__ F2F, const float* __restrict__ fc2b,
                 const unsigned int* __restrict__ bmask, float* __restrict__ out) {
  __shared__ __align__(16) unsigned short ybuf[64 * WPAD];    // 17408 B

  const int tid = threadIdx.x;
  const int wid = tid >> 6, lane = tid & 63;
  const int lr = lane & 15, lg = lane >> 4;
  const int row0 = blockIdx.x * 64;
  const float inv_n = 1.0f / (float)N_NODES;

  // dropout bitmask for this lane's 4 output rows (128 bits each)
  unsigned int bw[4][4];
#pragma unroll
  for (int r = 0; r < 4; ++r) {
    int row = row0 + wid * 16 + 4 * lg + r;
    if (row < N_NODES) {
      uint4 t = *reinterpret_cast<const uint4*>(bmask + (long)row * 4);
      bw[r][0] = t.x; bw[r][1] = t.y; bw[r][2] = t.z; bw[r][3] = t.w;
    } else {
      bw[r][0] = bw[r][1] = bw[r][2] = bw[r][3] = 0u;
    }
  }

  // A fragments: affine(z) in bf16
  bh8 afrag[4];
#pragma unroll
  for (int kk = 0; kk < 4; ++kk) {
    int k0 = kk * 32 + 8 * lg;
    fl4 s0, s1, bb0, bb1;
#pragma unroll
    for (int j = 0; j < 4; ++j) {
      int cc = k0 + j;
      float mean = stats[cc] * inv_n;
      float var  = stats[128 + cc] * inv_n - mean * mean;
      float sc   = gamma[cc] * rsqrtf(var + BN_EPS);
      s0[j] = sc; bb0[j] = beta[cc] - mean * sc;
    }
#pragma unroll
    for (int j = 0; j < 4; ++j) {
      int cc = k0 + 4 + j;
      float mean = stats[cc] * inv_n;
      float var  = stats[128 + cc] * inv_n - mean * mean;
      float sc   = gamma[cc] * rsqrtf(var + BN_EPS);
      s1[j] = sc; bb1[j] = beta[cc] - mean * sc;
    }
    int row = row0 + wid * 16 + lr;
    us8 t = (us8)0;
    if (row < N_NODES) {
      us8 zv = *reinterpret_cast<const us8*>(Z + (long)row * DIM_H + k0);
#pragma unroll
      for (int j = 0; j < 4; ++j) {
        t[j]     = f2bfbits(bf2f(zv[j])     * s0[j] + bb0[j]);
        t[4 + j] = f2bfbits(bf2f(zv[4 + j]) * s1[j] + bb1[j]);
      }
    }
    afrag[kk] = __builtin_bit_cast(bh8, t);
  }

  // GEMM1 + fc1b + relu + dropout -> ybuf
#pragma unroll
  for (int n0 = 0; n0 < 8; ++n0) {
    fl4 acc = {0.f, 0.f, 0.f, 0.f};
#pragma unroll
    for (int kk = 0; kk < 4; ++kk) {
      bh8 b = *reinterpret_cast<const bh8*>(&F1F[((n0 * 4 + kk) << 9) + lane * 8]);
      acc = __builtin_amdgcn_mfma_f32_16x16x32_bf16(afrag[kk], b, acc, 0, 0, 0);
    }
    float bias = fc1b[n0 * 16 + lr];
#pragma unroll
    for (int r = 0; r < 4; ++r) {
      float v = acc[r] + bias;
      v = v > 0.f ? v : 0.f;
      float mk = ((bw[r][n0 >> 1] >> (((n0 & 1) << 4) + lr)) & 1u) ? 2.0f : 0.0f;
      ybuf[(wid * 16 + 4 * lg + r) * WPAD + n0 * 16 + lr] = f2bfbits(v * mk);
    }
  }
  wave_lds_fence();

  bh8 a2[4];
#pragma unroll
  for (int kk = 0; kk < 4; ++kk)
    a2[kk] = *reinterpret_cast<const bh8*>(
        &ybuf[(wid * 16 + lr) * WPAD + kk * 32 + 8 * lg]);

  // GEMM2 (N=64)
  fl4 acc2[4];
#pragma unroll
  for (int n0 = 0; n0 < 4; ++n0) {
    acc2[n0] = (fl4){0.f, 0.f, 0.f, 0.f};
#pragma unroll
    for (int kk = 0; kk < 4; ++kk) {
      bh8 b = *reinterpret_cast<const bh8*>(&F2F[((n0 * 4 + kk) << 9) + lane * 8]);
      acc2[n0] = __builtin_amdgcn_mfma_f32_16x16x32_bf16(a2[kk], b, acc2[n0], 0, 0, 0);
    }
    float bias = fc2b[n0 * 16 + lr];
#pragma unroll
    for (int r = 0; r < 4; ++r) acc2[n0][r] += bias;
  }

  // log_softmax over 64 cols + store
#pragma unroll
  for (int r = 0; r < 4; ++r) {
    float m = fmaxf(fmaxf(acc2[0][r], acc2[1][r]), fmaxf(acc2[2][r], acc2[3][r]));
#pragma unroll
    for (int d = 1; d < 16; d <<= 1) m = fmaxf(m, __shfl_xor(m, d, 16));
    float se = 0.f;
#pragma unroll
    for (int n0 = 0; n0 < 4; ++n0) se += __expf(acc2[n0][r] - m);
#pragma unroll
    for (int d = 1; d < 16; d <<= 1) se += __shfl_xor(se, d, 16);
    float lse = m + __logf(se);
    int row = row0 + wid * 16 + 4 * lg + r;
    if (row < N_NODES) {
#pragma unroll
      for (int n0 = 0; n0 < 4; ++n0)
        out[(long)row * DIM_OUT + n0 * 16 + lr] = acc2[n0][r] - lse;
    }
  }
}

// ---------------- launcher ----------------
extern "C" void kernel_launch(void* const* d_in, const int* in_sizes, int n_in,
                              void* d_out, int out_size, void* d_ws, size_t ws_size,
                              hipStream_t stream) {
  const float* x      = (const float*)d_in[0];
  const int*   ei     = (const int*)d_in[1];
  const float* cw1    = (const float*)d_in[2];
  const float* cb1    = (const float*)d_in[3];
  const float* cw2    = (const float*)d_in[4];
  const float* cb2    = (const float*)d_in[5];
  const float* gamma  = (const float*)d_in[6];
  const float* beta   = (const float*)d_in[7];
  const float* fc1w   = (const float*)d_in[8];
  const float* fc1b   = (const float*)d_in[9];
  const float* fc2w   = (const float*)d_in[10];
  const float* fc2b   = (const float*)d_in[11];
  const float* mask   = (const float*)d_in[12];
  float* out = (float*)d_out;

  char* ws = (char*)d_ws;
  unsigned short* aggB  = (unsigned short*)ws;                 // 25,600,000 B
  unsigned short* Zb    = (unsigned short*)(ws + 25600000);    // 25,600,000 B (xB alias)
  unsigned short* W1F   = (unsigned short*)(ws + 51200000);    //     98,304 B
  unsigned short* W2F   = (unsigned short*)(ws + 51298304);    //     98,304 B
  unsigned short* F1F   = (unsigned short*)(ws + 51396608);    //     32,768 B
  unsigned short* F2F   = (unsigned short*)(ws + 51429376);    //     16,384 B
  float*          stats = (float*)(ws + 51445760);             //      3,072 B
  int*            rowst = (int*)(ws + 51448832);               //    400,004 B
  int*            cursor= (int*)(ws + 51848836);               //    400,000 B
  int*            csr   = (int*)(ws + 52248836);               //  2,400,000 B
  int*            bsum  = (int*)(ws + 54648836);               //      1,564 B
  int*            boff  = (int*)(ws + 54650400);               //      1,564 B
  unsigned int*   bmask = (unsigned int*)(ws + 54651968);      //  1,600,000 B
  if (ws_size < 56251968u) return;

  prep_kernel<<<NBLK, 256, 0, stream>>>(cw1, cw2, fc1w, fc2w, W1F, W2F, F1F, F2F,
                                        stats, cursor);        // cursor doubles as deg
  deg_xcast<<<12500, 256, 0, stream>>>(x, Zb, ei, cursor, mask, bmask); // xB -> Zb

  scanA<<<NBLK, 256, 0, stream>>>(cursor, rowst, bsum);
  scanB<<<1, 512, 0, stream>>>(bsum, boff);
  scanC<<<NBLK, 256, 0, stream>>>(rowst, boff, cursor);
  csr_fill<<<2344, 256, 0, stream>>>(ei, cursor, csr);

  // layer 0: gather bf16 x (in Zb) -> aggB; mlp overwrites Zb (xB dead)
  gather_h<0><<<25000, 256, 0, stream>>>(Zb, nullptr, nullptr, nullptr, rowst, csr, aggB);
  mlp_kernel<<<782, 256, 0, stream>>>(aggB, W1F, cb1, W2F, cb2, Zb, stats);

  // layer 1
  gather_h<1><<<25000, 256, 0, stream>>>(Zb, stats, gamma, beta, rowst, csr, aggB);
  mlp_kernel<<<782, 256, 0, stream>>>(aggB, W1F + 16384, cb1 + 128, W2F + 16384, cb2 + 128,
                                      Zb, stats + 256);

  // layer 2
  gather_h<1><<<25000, 256, 0, stream>>>(Zb, stats + 256, gamma + 128, beta + 128,
                                         rowst, csr, aggB);
  mlp_kernel<<<782, 256, 0, stream>>>(aggB, W1F + 32768, cb1 + 256, W2F + 32768, cb2 + 256,
                                      Zb, stats + 512);

  // head
  head_kernel<<<GRID64_HEAD, 256, 0, stream>>>(Zb, stats + 512, gamma + 256, beta + 256,
                                               F1F, fc1b, F2F, fc2b, bmask, out);
}